// Round 1
// baseline (13989.449 us; speedup 1.0000x reference)
//
#include <hip/hip_runtime.h>
#include <hip/hip_bf16.h>
#include <math.h>

// Problem: S=512, B=128, V=50257, D=300, H=512
#define S_LEN 512
#define B_N   128
#define D_EMB 300
#define KP    320   // D padded to multiple of 32 (zero-filled)
#define H_N   512

typedef __attribute__((ext_vector_type(8)))  short short8;       // 8 bf16 (4 VGPRs)
typedef __attribute__((ext_vector_type(8)))  unsigned short ushort8;
typedef __attribute__((ext_vector_type(4)))  float float4v;
typedef __attribute__((ext_vector_type(16))) float float16v;

__device__ __forceinline__ unsigned short f32_to_bf16(float f) {
  unsigned u = __float_as_uint(f);
  u = (u + 0x7fffu + ((u >> 16) & 1u)) >> 16;   // RNE
  return (unsigned short)u;
}
__device__ __forceinline__ float bf16_to_f32(unsigned short h) {
  return __uint_as_float(((unsigned)h) << 16);
}

// ---------------------------------------------------------------------------
// K1: embeds = embed_mat[ends]; xn = embeds / max(||embeds||,eps)
// writes xn as split bf16 (hi+lo), layout [b][s][KP], k 300..319 zero.
// One wave per (s,b) vector.
// ---------------------------------------------------------------------------
__global__ __launch_bounds__(256) void k1_embed_norm(
    const int* __restrict__ ends, const float* __restrict__ emb,
    unsigned short* __restrict__ xh, unsigned short* __restrict__ xl) {
  int wave = threadIdx.x >> 6, lane = threadIdx.x & 63;
  int vec = blockIdx.x * 4 + wave;            // vec = s*B + b (ends is [S][B])
  int b = vec & (B_N - 1), s = vec >> 7;
  int v = ends[vec];
  const float* row = emb + (size_t)v * D_EMB;
  float e0 = row[lane], e1 = row[lane + 64], e2 = row[lane + 128], e3 = row[lane + 192];
  float e4 = (lane + 256 < D_EMB) ? row[lane + 256] : 0.f;
  float ss = e0*e0 + e1*e1 + e2*e2 + e3*e3 + e4*e4;
  #pragma unroll
  for (int m = 1; m < 64; m <<= 1) ss += __shfl_xor(ss, m);
  float sc = 1.0f / fmaxf(sqrtf(ss), 1e-8f);
  size_t base = ((size_t)b * S_LEN + s) * KP;
  float xs[5] = { e0*sc, e1*sc, e2*sc, e3*sc, (lane + 256 < D_EMB) ? e4*sc : 0.f };
  #pragma unroll
  for (int i = 0; i < 5; ++i) {
    unsigned short hi = f32_to_bf16(xs[i]);
    unsigned short lo = f32_to_bf16(xs[i] - bf16_to_f32(hi));
    xh[base + lane + 64*i] = hi;
    xl[base + lane + 64*i] = lo;
  }
}

// ---------------------------------------------------------------------------
// K2: feats[i][b] = max_{j<i} dot(xn[i,b], xn[j,b]); feats[0]=0
// Split-bf16 MFMA 32x32x16 (hi*hi + hi*lo + lo*hi).
// WG = (b, i-chunk of 64). waves: (it_local = w&1, jt_local = w>>1).
// Loops j-chunks (64) x k-chunks (80), single-buffered LDS staging.
// ---------------------------------------------------------------------------
#define KC  80
#define LDP 88      // LDS row stride in ushorts (conflict-friendly, 16B aligned)

__global__ __launch_bounds__(256) void k2_feats(
    const unsigned short* __restrict__ xh, const unsigned short* __restrict__ xl,
    float* __restrict__ feats) {
  __shared__ __align__(16) unsigned short sAh[64*LDP], sAl[64*LDP], sBh[64*LDP], sBl[64*LDP];
  __shared__ float rbuf[4][32];
  int ic  = blockIdx.x;          // 0..7
  int b   = blockIdx.y;          // 0..127
  int tid = threadIdx.x;
  int wave = tid >> 6, lane = tid & 63;
  int itl = wave & 1, jtl = wave >> 1;
  int itg = ic * 2 + itl;        // global 32-row i-tile index
  size_t xbase = (size_t)b * S_LEN * KP;
  int arow0 = ic * 64;

  float rm[16];
  #pragma unroll
  for (int r = 0; r < 16; ++r) rm[r] = -INFINITY;

  for (int jc = 0; jc <= ic; ++jc) {
    int jt = jc * 2 + jtl;
    bool active = (jt <= itg);
    float16v acc;
    #pragma unroll
    for (int r = 0; r < 16; ++r) acc[r] = 0.f;

    for (int kc = 0; kc < 4; ++kc) {
      __syncthreads();
      for (int u = tid; u < 640; u += 256) {     // 64 rows x 10 16B-segs
        int r = u / 10, sg = u % 10;
        size_t ga = xbase + (size_t)(arow0 + r) * KP + kc*KC + sg*8;
        size_t gb = xbase + (size_t)(jc*64 + r) * KP + kc*KC + sg*8;
        int la = r * LDP + sg * 8;
        *(ushort8*)&sAh[la] = *(const ushort8*)&xh[ga];
        *(ushort8*)&sAl[la] = *(const ushort8*)&xl[ga];
        *(ushort8*)&sBh[la] = *(const ushort8*)&xh[gb];
        *(ushort8*)&sBl[la] = *(const ushort8*)&xl[gb];
      }
      __syncthreads();
      if (active) {
        int ar = (itl*32 + (lane & 31)) * LDP;
        int br = (jtl*32 + (lane & 31)) * LDP;
        int kq = (lane >> 5) * 8;
        #pragma unroll
        for (int ks = 0; ks < 5; ++ks) {
          short8 a_h = *(const short8*)&sAh[ar + ks*16 + kq];
          short8 a_l = *(const short8*)&sAl[ar + ks*16 + kq];
          short8 b_h = *(const short8*)&sBh[br + ks*16 + kq];
          short8 b_l = *(const short8*)&sBl[br + ks*16 + kq];
          acc = __builtin_amdgcn_mfma_f32_32x32x16_bf16(a_h, b_h, acc, 0, 0, 0);
          acc = __builtin_amdgcn_mfma_f32_32x32x16_bf16(a_h, b_l, acc, 0, 0, 0);
          acc = __builtin_amdgcn_mfma_f32_32x32x16_bf16(a_l, b_h, acc, 0, 0, 0);
        }
      }
    }
    if (active) {
      int colg = jt * 32 + (lane & 31);
      #pragma unroll
      for (int r = 0; r < 16; ++r) {
        int rowg = itg * 32 + (r & 3) + 8*(r >> 2) + 4*(lane >> 5);
        float v = acc[r];
        if (jt == itg && colg >= rowg) v = -INFINITY;  // causal: j<i
        rm[r] = fmaxf(rm[r], v);
      }
    }
  }
  // max over the 32 columns (lanes sharing lane>>5)
  #pragma unroll
  for (int r = 0; r < 16; ++r) {
    float v = rm[r];
    v = fmaxf(v, __shfl_xor(v, 1));
    v = fmaxf(v, __shfl_xor(v, 2));
    v = fmaxf(v, __shfl_xor(v, 4));
    v = fmaxf(v, __shfl_xor(v, 8));
    v = fmaxf(v, __shfl_xor(v, 16));
    rm[r] = v;
  }
  if ((lane & 31) == 0) {
    int half = lane >> 5;
    #pragma unroll
    for (int r = 0; r < 16; ++r)
      rbuf[wave][(r & 3) + 8*(r >> 2) + 4*half] = rm[r];
  }
  __syncthreads();
  if (tid < 64) {   // merge jt-parities, write feats
    int it2 = tid >> 5, rl = tid & 31;
    float v = fmaxf(rbuf[it2][rl], rbuf[it2 + 2][rl]);
    int i = ic * 64 + it2 * 32 + rl;
    feats[i * B_N + b] = (i == 0) ? 0.0f : v;
  }
}

// ---------------------------------------------------------------------------
// K3: GRU, persistent cooperative kernel. 256 WGs x 256 thr.
// group g = blockIdx&7 (16 batches, XCD-local), slice s = blockIdx>>3 (16 j's).
// W_hh fragments (split bf16) live in registers for all 512 steps.
// Per step: 36 MFMA 16x16x32 per wave (K split 4 ways across waves),
// LDS reduce, fp32 gates, h published split-bf16 (double-buffered),
// one release/acquire 32-WG barrier per step. Epilogue: fc head via atomics.
// ---------------------------------------------------------------------------
__global__ __launch_bounds__(256, 1) void k3_gru(
    const float* __restrict__ feats,
    const float* __restrict__ w_ih, const float* __restrict__ w_hh,
    const float* __restrict__ b_ih, const float* __restrict__ b_hh,
    const float* __restrict__ fc_w, const float* __restrict__ fc_b,
    unsigned short* __restrict__ hh, unsigned short* __restrict__ hl,
    unsigned int* __restrict__ bars, float* __restrict__ out) {
  __shared__ float red[4][3][256];
  __shared__ float osum[256];
  int tid = threadIdx.x;
  int wave = tid >> 6, lane = tid & 63;
  int g = blockIdx.x & 7, s = blockIdx.x >> 3;

  // --- stationary W_hh fragments in registers (B-operand: n=lane&15, k=quad*8+j)
  short8 wfh[3][4], wfl[3][4];
  {
    int nloc = lane & 15;
    int kq = (lane >> 4) * 8;
    #pragma unroll
    for (int gt = 0; gt < 3; ++gt) {
      const float* wr = w_hh + (size_t)(gt * H_N + s * 16 + nloc) * H_N;
      #pragma unroll
      for (int ks = 0; ks < 4; ++ks) {
        int k0 = wave * 128 + ks * 32 + kq;
        short8 h8, l8;
        #pragma unroll
        for (int j = 0; j < 8; ++j) {
          float wv = wr[k0 + j];
          unsigned short hi = f32_to_bf16(wv);
          unsigned short lo = f32_to_bf16(wv - bf16_to_f32(hi));
          h8[j] = (short)hi; l8[j] = (short)lo;
        }
        wfh[gt][ks] = h8; wfl[gt][ks] = l8;
      }
    }
  }
  // --- per-thread gate constants: thread = (bb, jj)
  int bb = tid >> 4, jj = tid & 15;
  int jr = s * 16 + jj;
  float wihr = w_ih[jr], wihz = w_ih[H_N + jr], wihn = w_ih[2*H_N + jr];
  float bir = b_ih[jr],  biz = b_ih[H_N + jr],  bin_ = b_ih[2*H_N + jr];
  float bhr = b_hh[jr],  bhz = b_hh[H_N + jr],  bhn = b_hh[2*H_N + jr];
  float fcw = fc_w[jr];
  int gb = g * 16 + bb;
  float h_old = 0.f;
  unsigned int* bar = bars + g * 64;            // 256B-spread per group
  const size_t BH = (size_t)B_N * H_N;
  int arow = g * 16 + (lane & 15);              // A-operand m = batch
  int kqa = (lane >> 4) * 8;

  for (int t = 0; t < S_LEN; ++t) {
    float sr = 0.f, sz = 0.f, sn = 0.f;
    if (t > 0) {
      int ri = (t - 1) & 1;
      const unsigned short* ph = hh + ri * BH + (size_t)arow * H_N;
      const unsigned short* pl = hl + ri * BH + (size_t)arow * H_N;
      short8 ah[4], al[4];
      #pragma unroll
      for (int ks = 0; ks < 4; ++ks) {
        int k0 = wave * 128 + ks * 32 + kqa;
        ah[ks] = *(const short8*)(ph + k0);
        al[ks] = *(const short8*)(pl + k0);
      }
      float4v a0, a1, a2;
      #pragma unroll
      for (int r = 0; r < 4; ++r) { a0[r] = 0.f; a1[r] = 0.f; a2[r] = 0.f; }
      #pragma unroll
      for (int ks = 0; ks < 4; ++ks) {
        a0 = __builtin_amdgcn_mfma_f32_16x16x32_bf16(ah[ks], wfh[0][ks], a0, 0,0,0);
        a1 = __builtin_amdgcn_mfma_f32_16x16x32_bf16(ah[ks], wfh[1][ks], a1, 0,0,0);
        a2 = __builtin_amdgcn_mfma_f32_16x16x32_bf16(ah[ks], wfh[2][ks], a2, 0,0,0);
        a0 = __builtin_amdgcn_mfma_f32_16x16x32_bf16(ah[ks], wfl[0][ks], a0, 0,0,0);
        a1 = __builtin_amdgcn_mfma_f32_16x16x32_bf16(ah[ks], wfl[1][ks], a1, 0,0,0);
        a2 = __builtin_amdgcn_mfma_f32_16x16x32_bf16(ah[ks], wfl[2][ks], a2, 0,0,0);
        a0 = __builtin_amdgcn_mfma_f32_16x16x32_bf16(al[ks], wfh[0][ks], a0, 0,0,0);
        a1 = __builtin_amdgcn_mfma_f32_16x16x32_bf16(al[ks], wfh[1][ks], a1, 0,0,0);
        a2 = __builtin_amdgcn_mfma_f32_16x16x32_bf16(al[ks], wfh[2][ks], a2, 0,0,0);
      }
      // C/D: row(batch)=(lane>>4)*4+reg, col(j)=lane&15. Store [col][row] for b128.
      int colw = lane & 15, roww = (lane >> 4) * 4;
      *(float4v*)&red[wave][0][colw * 16 + roww] = a0;
      *(float4v*)&red[wave][1][colw * 16 + roww] = a1;
      *(float4v*)&red[wave][2][colw * 16 + roww] = a2;
      __syncthreads();
      int ridx = jj * 16 + bb;
      sr = red[0][0][ridx] + red[1][0][ridx] + red[2][0][ridx] + red[3][0][ridx];
      sz = red[0][1][ridx] + red[1][1][ridx] + red[2][1][ridx] + red[3][1][ridx];
      sn = red[0][2][ridx] + red[1][2][ridx] + red[2][2][ridx] + red[3][2][ridx];
    }
    float x = feats[t * B_N + gb];
    float r_ = 1.f / (1.f + expf(-(x * wihr + bir + sr + bhr)));
    float z_ = 1.f / (1.f + expf(-(x * wihz + biz + sz + bhz)));
    float n_ = tanhf(x * wihn + bin_ + r_ * (sn + bhn));
    float h_new = (1.f - z_) * n_ + z_ * h_old;
    h_old = h_new;
    {
      int wi = t & 1;
      unsigned short hi16 = f32_to_bf16(h_new);
      unsigned short lo16 = f32_to_bf16(h_new - bf16_to_f32(hi16));
      size_t ha = wi * BH + (size_t)gb * H_N + jr;
      hh[ha] = hi16; hl[ha] = lo16;
    }
    if (t < S_LEN - 1) {
      __threadfence();
      __syncthreads();
      if (tid == 0) {
        __hip_atomic_fetch_add(bar, 1u, __ATOMIC_RELEASE, __HIP_MEMORY_SCOPE_AGENT);
        unsigned int target = 32u * (unsigned)(t + 1);
        while (__hip_atomic_load(bar, __ATOMIC_ACQUIRE, __HIP_MEMORY_SCOPE_AGENT) < target)
          __builtin_amdgcn_s_sleep(2);
      }
      __syncthreads();
    }
  }
  // --- epilogue: out[b] = h_last . fc_w + fc_b
  osum[tid] = h_old * fcw;
  __syncthreads();
  if (jj == 0) {
    float acc = 0.f;
    #pragma unroll
    for (int q = 0; q < 16; ++q) acc += osum[bb * 16 + q];
    if (s == 0) acc += fc_b[0];
    atomicAdd(&out[gb], acc);
  }
}

// ---------------------------------------------------------------------------
extern "C" void kernel_launch(void* const* d_in, const int* in_sizes, int n_in,
                              void* d_out, int out_size, void* d_ws, size_t ws_size,
                              hipStream_t stream) {
  (void)in_sizes; (void)n_in; (void)out_size; (void)ws_size;
  const int*   ends = (const int*)d_in[1];
  const float* emb  = (const float*)d_in[3];
  const float* w_ih = (const float*)d_in[4];
  const float* w_hh = (const float*)d_in[5];
  const float* b_ih = (const float*)d_in[6];
  const float* b_hh = (const float*)d_in[7];
  const float* fc_w = (const float*)d_in[8];
  const float* fc_b = (const float*)d_in[9];
  float* out = (float*)d_out;

  size_t xn_elems = (size_t)B_N * S_LEN * KP;
  unsigned short* xh = (unsigned short*)d_ws;
  unsigned short* xl = xh + xn_elems;
  float* feats = (float*)(xl + xn_elems);
  unsigned short* hh = (unsigned short*)(feats + S_LEN * B_N);
  unsigned short* hl = hh + 2 * (size_t)B_N * H_N;
  unsigned int* bars = (unsigned int*)(hl + 2 * (size_t)B_N * H_N);

  hipMemsetAsync(out, 0, sizeof(float) * B_N, stream);
  hipMemsetAsync(bars, 0, 4096, stream);

  k1_embed_norm<<<dim3(S_LEN * B_N / 4), dim3(256), 0, stream>>>(ends, emb, xh, xl);
  k2_feats<<<dim3(8, B_N), dim3(256), 0, stream>>>(xh, xl, feats);

  void* args[] = { (void*)&feats, (void*)&w_ih, (void*)&w_hh, (void*)&b_ih,
                   (void*)&b_hh, (void*)&fc_w, (void*)&fc_b,
                   (void*)&hh, (void*)&hl, (void*)&bars, (void*)&out };
  hipLaunchCooperativeKernel((void*)k3_gru, dim3(256), dim3(256), args, 0, stream);
}

// Round 2
// 2613.180 us; speedup vs baseline: 5.3534x; 5.3534x over previous
//
#include <hip/hip_runtime.h>
#include <hip/hip_bf16.h>
#include <math.h>

// Problem: S=512, B=128, V=50257, D=300, H=512
#define S_LEN 512
#define B_N   128
#define D_EMB 300
#define KP    320   // D padded to multiple of 32 (zero-filled)
#define H_N   512

typedef __attribute__((ext_vector_type(8)))  short short8;       // 8 bf16 (4 VGPRs)
typedef __attribute__((ext_vector_type(8)))  unsigned short ushort8;
typedef __attribute__((ext_vector_type(4)))  float float4v;
typedef __attribute__((ext_vector_type(16))) float float16v;

__device__ __forceinline__ unsigned short f32_to_bf16(float f) {
  unsigned u = __float_as_uint(f);
  u = (u + 0x7fffu + ((u >> 16) & 1u)) >> 16;   // RNE
  return (unsigned short)u;
}
__device__ __forceinline__ float bf16_to_f32(unsigned short h) {
  return __uint_as_float(((unsigned)h) << 16);
}

// ---------------------------------------------------------------------------
// K1: embeds = embed_mat[ends]; xn = embeds / max(||embeds||,eps)
// writes xn as split bf16 (hi+lo), layout [b][s][KP], k 300..319 zero.
// One wave per (s,b) vector.
// ---------------------------------------------------------------------------
__global__ __launch_bounds__(256) void k1_embed_norm(
    const int* __restrict__ ends, const float* __restrict__ emb,
    unsigned short* __restrict__ xh, unsigned short* __restrict__ xl) {
  int wave = threadIdx.x >> 6, lane = threadIdx.x & 63;
  int vec = blockIdx.x * 4 + wave;            // vec = s*B + b (ends is [S][B])
  int b = vec & (B_N - 1), s = vec >> 7;
  int v = ends[vec];
  const float* row = emb + (size_t)v * D_EMB;
  float e0 = row[lane], e1 = row[lane + 64], e2 = row[lane + 128], e3 = row[lane + 192];
  float e4 = (lane + 256 < D_EMB) ? row[lane + 256] : 0.f;
  float ss = e0*e0 + e1*e1 + e2*e2 + e3*e3 + e4*e4;
  #pragma unroll
  for (int m = 1; m < 64; m <<= 1) ss += __shfl_xor(ss, m);
  float sc = 1.0f / fmaxf(sqrtf(ss), 1e-8f);
  size_t base = ((size_t)b * S_LEN + s) * KP;
  float xs[5] = { e0*sc, e1*sc, e2*sc, e3*sc, (lane + 256 < D_EMB) ? e4*sc : 0.f };
  #pragma unroll
  for (int i = 0; i < 5; ++i) {
    unsigned short hi = f32_to_bf16(xs[i]);
    unsigned short lo = f32_to_bf16(xs[i] - bf16_to_f32(hi));
    xh[base + lane + 64*i] = hi;
    xl[base + lane + 64*i] = lo;
  }
}

// ---------------------------------------------------------------------------
// K2: feats[i][b] = max_{j<i} dot(xn[i,b], xn[j,b]); feats[0]=0
// Split-bf16 MFMA 32x32x16 (hi*hi + hi*lo + lo*hi).
// ---------------------------------------------------------------------------
#define KC  80
#define LDP 88      // LDS row stride in ushorts (conflict-friendly, 16B aligned)

__global__ __launch_bounds__(256) void k2_feats(
    const unsigned short* __restrict__ xh, const unsigned short* __restrict__ xl,
    float* __restrict__ feats) {
  __shared__ __align__(16) unsigned short sAh[64*LDP], sAl[64*LDP], sBh[64*LDP], sBl[64*LDP];
  __shared__ float rbuf[4][32];
  int ic  = blockIdx.x;          // 0..7
  int b   = blockIdx.y;          // 0..127
  int tid = threadIdx.x;
  int wave = tid >> 6, lane = tid & 63;
  int itl = wave & 1, jtl = wave >> 1;
  int itg = ic * 2 + itl;        // global 32-row i-tile index
  size_t xbase = (size_t)b * S_LEN * KP;
  int arow0 = ic * 64;

  float rm[16];
  #pragma unroll
  for (int r = 0; r < 16; ++r) rm[r] = -INFINITY;

  for (int jc = 0; jc <= ic; ++jc) {
    int jt = jc * 2 + jtl;
    bool active = (jt <= itg);
    float16v acc;
    #pragma unroll
    for (int r = 0; r < 16; ++r) acc[r] = 0.f;

    for (int kc = 0; kc < 4; ++kc) {
      __syncthreads();
      for (int u = tid; u < 640; u += 256) {     // 64 rows x 10 16B-segs
        int r = u / 10, sg = u % 10;
        size_t ga = xbase + (size_t)(arow0 + r) * KP + kc*KC + sg*8;
        size_t gb = xbase + (size_t)(jc*64 + r) * KP + kc*KC + sg*8;
        int la = r * LDP + sg * 8;
        *(ushort8*)&sAh[la] = *(const ushort8*)&xh[ga];
        *(ushort8*)&sAl[la] = *(const ushort8*)&xl[ga];
        *(ushort8*)&sBh[la] = *(const ushort8*)&xh[gb];
        *(ushort8*)&sBl[la] = *(const ushort8*)&xl[gb];
      }
      __syncthreads();
      if (active) {
        int ar = (itl*32 + (lane & 31)) * LDP;
        int br = (jtl*32 + (lane & 31)) * LDP;
        int kq = (lane >> 5) * 8;
        #pragma unroll
        for (int ks = 0; ks < 5; ++ks) {
          short8 a_h = *(const short8*)&sAh[ar + ks*16 + kq];
          short8 a_l = *(const short8*)&sAl[ar + ks*16 + kq];
          short8 b_h = *(const short8*)&sBh[br + ks*16 + kq];
          short8 b_l = *(const short8*)&sBl[br + ks*16 + kq];
          acc = __builtin_amdgcn_mfma_f32_32x32x16_bf16(a_h, b_h, acc, 0, 0, 0);
          acc = __builtin_amdgcn_mfma_f32_32x32x16_bf16(a_h, b_l, acc, 0, 0, 0);
          acc = __builtin_amdgcn_mfma_f32_32x32x16_bf16(a_l, b_h, acc, 0, 0, 0);
        }
      }
    }
    if (active) {
      int colg = jt * 32 + (lane & 31);
      #pragma unroll
      for (int r = 0; r < 16; ++r) {
        int rowg = itg * 32 + (r & 3) + 8*(r >> 2) + 4*(lane >> 5);
        float v = acc[r];
        if (jt == itg && colg >= rowg) v = -INFINITY;  // causal: j<i
        rm[r] = fmaxf(rm[r], v);
      }
    }
  }
  // max over the 32 columns (lanes sharing lane>>5)
  #pragma unroll
  for (int r = 0; r < 16; ++r) {
    float v = rm[r];
    v = fmaxf(v, __shfl_xor(v, 1));
    v = fmaxf(v, __shfl_xor(v, 2));
    v = fmaxf(v, __shfl_xor(v, 4));
    v = fmaxf(v, __shfl_xor(v, 8));
    v = fmaxf(v, __shfl_xor(v, 16));
    rm[r] = v;
  }
  if ((lane & 31) == 0) {
    int half = lane >> 5;
    #pragma unroll
    for (int r = 0; r < 16; ++r)
      rbuf[wave][(r & 3) + 8*(r >> 2) + 4*half] = rm[r];
  }
  __syncthreads();
  if (tid < 64) {   // merge jt-parities, write feats
    int it2 = tid >> 5, rl = tid & 31;
    float v = fmaxf(rbuf[it2][rl], rbuf[it2 + 2][rl]);
    int i = ic * 64 + it2 * 32 + rl;
    feats[i * B_N + b] = (i == 0) ? 0.0f : v;
  }
}

// ---------------------------------------------------------------------------
// K3: GRU, persistent cooperative kernel. 256 WGs x 256 thr.
// group g = blockIdx&7 (16 batches), slice s = blockIdx>>3 (16 j's).
// W_hh fragments (split bf16) stationary in registers for all 512 steps.
// h exchange: RELAXED agent-scope atomics only (cache-bypass, NO wbl2/inv),
// data->flag ordering via raw s_waitcnt vmcnt(0). h stored as two uint-word
// planes (hi-pairs / lo-pairs) so readers use 64-bit relaxed atomic loads
// that bitcast straight into short8 MFMA fragments.
// ---------------------------------------------------------------------------
#define HW2 (B_N * H_N / 2)   // uints per plane per buffer

__global__ __launch_bounds__(256, 1) void k3_gru(
    const float* __restrict__ feats,
    const float* __restrict__ w_ih, const float* __restrict__ w_hh,
    const float* __restrict__ b_ih, const float* __restrict__ b_hh,
    const float* __restrict__ fc_w, const float* __restrict__ fc_b,
    unsigned int* __restrict__ hhw, unsigned int* __restrict__ hlw,
    unsigned int* __restrict__ bars, float* __restrict__ out) {
  __shared__ float red[4][3][256];
  __shared__ float osum[256];
  int tid = threadIdx.x;
  int wave = tid >> 6, lane = tid & 63;
  int g = blockIdx.x & 7, s = blockIdx.x >> 3;

  // --- stationary W_hh fragments in registers (B-operand: n=lane&15, k=quad*8+j)
  short8 wfh[3][4], wfl[3][4];
  {
    int nloc = lane & 15;
    int kq = (lane >> 4) * 8;
    #pragma unroll
    for (int gt = 0; gt < 3; ++gt) {
      const float* wr = w_hh + (size_t)(gt * H_N + s * 16 + nloc) * H_N;
      #pragma unroll
      for (int ks = 0; ks < 4; ++ks) {
        int k0 = wave * 128 + ks * 32 + kq;
        short8 h8, l8;
        #pragma unroll
        for (int j = 0; j < 8; ++j) {
          float wv = wr[k0 + j];
          unsigned short hi = f32_to_bf16(wv);
          unsigned short lo = f32_to_bf16(wv - bf16_to_f32(hi));
          h8[j] = (short)hi; l8[j] = (short)lo;
        }
        wfh[gt][ks] = h8; wfl[gt][ks] = l8;
      }
    }
  }
  // --- per-thread gate constants: thread = (bb, jj)
  int bb = tid >> 4, jj = tid & 15;
  int jr = s * 16 + jj;
  float wihr = w_ih[jr], wihz = w_ih[H_N + jr], wihn = w_ih[2*H_N + jr];
  float bir = b_ih[jr],  biz = b_ih[H_N + jr],  bin_ = b_ih[2*H_N + jr];
  float bhr = b_hh[jr],  bhz = b_hh[H_N + jr],  bhn = b_hh[2*H_N + jr];
  float fcw = fc_w[jr];
  int gb = g * 16 + bb;
  float h_old = 0.f;
  unsigned int* bar = bars + g * 64;            // 256B-spread per group
  int arow = g * 16 + (lane & 15);              // A-operand m = batch
  int kqa = (lane >> 4) * 8;
  size_t widx = ((size_t)gb * H_N + jr) >> 1;   // h word index for this thread

  for (int t = 0; t < S_LEN; ++t) {
    float sr = 0.f, sz = 0.f, sn = 0.f;
    if (t > 0) {
      int ri = (t - 1) & 1;
      const unsigned int* bh = hhw + (size_t)ri * HW2 + (((size_t)arow * H_N) >> 1);
      const unsigned int* bl = hlw + (size_t)ri * HW2 + (((size_t)arow * H_N) >> 1);
      short8 ah[4], al[4];
      #pragma unroll
      for (int ks = 0; ks < 4; ++ks) {
        int kw = (wave * 128 + ks * 32 + kqa) >> 1;   // uint index, 8B aligned
        union { unsigned long long q[2]; short8 v; } uh, ul;
        const unsigned long long* p8h = (const unsigned long long*)(bh + kw);
        const unsigned long long* p8l = (const unsigned long long*)(bl + kw);
        uh.q[0] = __hip_atomic_load(p8h,     __ATOMIC_RELAXED, __HIP_MEMORY_SCOPE_AGENT);
        uh.q[1] = __hip_atomic_load(p8h + 1, __ATOMIC_RELAXED, __HIP_MEMORY_SCOPE_AGENT);
        ul.q[0] = __hip_atomic_load(p8l,     __ATOMIC_RELAXED, __HIP_MEMORY_SCOPE_AGENT);
        ul.q[1] = __hip_atomic_load(p8l + 1, __ATOMIC_RELAXED, __HIP_MEMORY_SCOPE_AGENT);
        ah[ks] = uh.v; al[ks] = ul.v;
      }
      float4v a0, a1, a2;
      #pragma unroll
      for (int r = 0; r < 4; ++r) { a0[r] = 0.f; a1[r] = 0.f; a2[r] = 0.f; }
      #pragma unroll
      for (int ks = 0; ks < 4; ++ks) {
        a0 = __builtin_amdgcn_mfma_f32_16x16x32_bf16(ah[ks], wfh[0][ks], a0, 0,0,0);
        a1 = __builtin_amdgcn_mfma_f32_16x16x32_bf16(ah[ks], wfh[1][ks], a1, 0,0,0);
        a2 = __builtin_amdgcn_mfma_f32_16x16x32_bf16(ah[ks], wfh[2][ks], a2, 0,0,0);
        a0 = __builtin_amdgcn_mfma_f32_16x16x32_bf16(ah[ks], wfl[0][ks], a0, 0,0,0);
        a1 = __builtin_amdgcn_mfma_f32_16x16x32_bf16(ah[ks], wfl[1][ks], a1, 0,0,0);
        a2 = __builtin_amdgcn_mfma_f32_16x16x32_bf16(ah[ks], wfl[2][ks], a2, 0,0,0);
        a0 = __builtin_amdgcn_mfma_f32_16x16x32_bf16(al[ks], wfh[0][ks], a0, 0,0,0);
        a1 = __builtin_amdgcn_mfma_f32_16x16x32_bf16(al[ks], wfh[1][ks], a1, 0,0,0);
        a2 = __builtin_amdgcn_mfma_f32_16x16x32_bf16(al[ks], wfh[2][ks], a2, 0,0,0);
      }
      // C/D: row(batch)=(lane>>4)*4+reg, col(j)=lane&15. Store [col][row] for b128.
      int colw = lane & 15, roww = (lane >> 4) * 4;
      *(float4v*)&red[wave][0][colw * 16 + roww] = a0;
      *(float4v*)&red[wave][1][colw * 16 + roww] = a1;
      *(float4v*)&red[wave][2][colw * 16 + roww] = a2;
      __syncthreads();
      int ridx = jj * 16 + bb;
      sr = red[0][0][ridx] + red[1][0][ridx] + red[2][0][ridx] + red[3][0][ridx];
      sz = red[0][1][ridx] + red[1][1][ridx] + red[2][1][ridx] + red[3][1][ridx];
      sn = red[0][2][ridx] + red[1][2][ridx] + red[2][2][ridx] + red[3][2][ridx];
    }
    float x = feats[t * B_N + gb];
    float r_ = 1.f / (1.f + expf(-(x * wihr + bir + sr + bhr)));
    float z_ = 1.f / (1.f + expf(-(x * wihz + biz + sz + bhz)));
    float n_ = tanhf(x * wihn + bin_ + r_ * (sn + bhn));
    float h_new = (1.f - z_) * n_ + z_ * h_old;
    h_old = h_new;
    {
      int wi = t & 1;
      unsigned short hi16 = f32_to_bf16(h_new);
      unsigned short lo16 = f32_to_bf16(h_new - bf16_to_f32(hi16));
      unsigned packed = (unsigned)hi16 | ((unsigned)lo16 << 16);
      unsigned other = (unsigned)__shfl_xor((int)packed, 1);
      if ((jj & 1) == 0) {  // hi-plane word: hi(j0) | hi(j1)<<16
        unsigned w = (packed & 0xffffu) | (other << 16);
        __hip_atomic_store(&hhw[(size_t)wi * HW2 + widx], w,
                           __ATOMIC_RELAXED, __HIP_MEMORY_SCOPE_AGENT);
      } else {              // lo-plane word: lo(j0) | lo(j1)<<16
        unsigned w = (other >> 16) | (packed & 0xffff0000u);
        __hip_atomic_store(&hlw[(size_t)wi * HW2 + widx], w,
                           __ATOMIC_RELAXED, __HIP_MEMORY_SCOPE_AGENT);
      }
    }
    if (t < S_LEN - 1) {
      // data->flag ordering: store acks (coherence point) before flag add
      asm volatile("s_waitcnt vmcnt(0)" ::: "memory");
      __syncthreads();
      if (tid == 0) {
        __hip_atomic_fetch_add(bar, 1u, __ATOMIC_RELAXED, __HIP_MEMORY_SCOPE_AGENT);
        unsigned int target = 32u * (unsigned)(t + 1);
        while (__hip_atomic_load(bar, __ATOMIC_RELAXED, __HIP_MEMORY_SCOPE_AGENT) < target)
          __builtin_amdgcn_s_sleep(1);
      }
      __syncthreads();
      asm volatile("" ::: "memory");
    }
  }
  // --- epilogue: out[b] = h_last . fc_w + fc_b
  osum[tid] = h_old * fcw;
  __syncthreads();
  if (jj == 0) {
    float acc = 0.f;
    #pragma unroll
    for (int q = 0; q < 16; ++q) acc += osum[bb * 16 + q];
    if (s == 0) acc += fc_b[0];
    atomicAdd(&out[gb], acc);
  }
}

// ---------------------------------------------------------------------------
extern "C" void kernel_launch(void* const* d_in, const int* in_sizes, int n_in,
                              void* d_out, int out_size, void* d_ws, size_t ws_size,
                              hipStream_t stream) {
  (void)in_sizes; (void)n_in; (void)out_size; (void)ws_size;
  const int*   ends = (const int*)d_in[1];
  const float* emb  = (const float*)d_in[3];
  const float* w_ih = (const float*)d_in[4];
  const float* w_hh = (const float*)d_in[5];
  const float* b_ih = (const float*)d_in[6];
  const float* b_hh = (const float*)d_in[7];
  const float* fc_w = (const float*)d_in[8];
  const float* fc_b = (const float*)d_in[9];
  float* out = (float*)d_out;

  size_t xn_elems = (size_t)B_N * S_LEN * KP;
  unsigned short* xh = (unsigned short*)d_ws;
  unsigned short* xl = xh + xn_elems;
  float* feats = (float*)(xl + xn_elems);
  unsigned int* hhw = (unsigned int*)(feats + S_LEN * B_N);
  unsigned int* hlw = hhw + 2 * (size_t)HW2;
  unsigned int* bars = hlw + 2 * (size_t)HW2;

  hipMemsetAsync(out, 0, sizeof(float) * B_N, stream);
  hipMemsetAsync(bars, 0, 4096, stream);

  k1_embed_norm<<<dim3(S_LEN * B_N / 4), dim3(256), 0, stream>>>(ends, emb, xh, xl);
  k2_feats<<<dim3(8, B_N), dim3(256), 0, stream>>>(xh, xl, feats);

  void* args[] = { (void*)&feats, (void*)&w_ih, (void*)&w_hh, (void*)&b_ih,
                   (void*)&b_hh, (void*)&fc_w, (void*)&fc_b,
                   (void*)&hhw, (void*)&hlw, (void*)&bars, (void*)&out };
  hipLaunchCooperativeKernel((void*)k3_gru, dim3(256), dim3(256), args, 0, stream);
}

// Round 3
// 2225.448 us; speedup vs baseline: 6.2861x; 1.1742x over previous
//
#include <hip/hip_runtime.h>
#include <hip/hip_bf16.h>
#include <math.h>

// Problem: S=512, B=128, V=50257, D=300, H=512
#define S_LEN 512
#define B_N   128
#define D_EMB 300
#define KP    320   // D padded to multiple of 32 (zero-filled)
#define H_N   512

typedef __attribute__((ext_vector_type(8)))  short short8;       // 8 bf16 (4 VGPRs)
typedef __attribute__((ext_vector_type(8)))  unsigned short ushort8;
typedef __attribute__((ext_vector_type(4)))  float float4v;
typedef __attribute__((ext_vector_type(16))) float float16v;

__device__ __forceinline__ unsigned short f32_to_bf16(float f) {
  unsigned u = __float_as_uint(f);
  u = (u + 0x7fffu + ((u >> 16) & 1u)) >> 16;   // RNE
  return (unsigned short)u;
}
__device__ __forceinline__ float bf16_to_f32(unsigned short h) {
  return __uint_as_float(((unsigned)h) << 16);
}

// ---------------------------------------------------------------------------
// K1: embeds = embed_mat[ends]; xn = embeds / max(||embeds||,eps)
// writes xn as split bf16 (hi+lo), layout [b][s][KP], k 300..319 zero.
// ---------------------------------------------------------------------------
__global__ __launch_bounds__(256) void k1_embed_norm(
    const int* __restrict__ ends, const float* __restrict__ emb,
    unsigned short* __restrict__ xh, unsigned short* __restrict__ xl) {
  int wave = threadIdx.x >> 6, lane = threadIdx.x & 63;
  int vec = blockIdx.x * 4 + wave;            // vec = s*B + b (ends is [S][B])
  int b = vec & (B_N - 1), s = vec >> 7;
  int v = ends[vec];
  const float* row = emb + (size_t)v * D_EMB;
  float e0 = row[lane], e1 = row[lane + 64], e2 = row[lane + 128], e3 = row[lane + 192];
  float e4 = (lane + 256 < D_EMB) ? row[lane + 256] : 0.f;
  float ss = e0*e0 + e1*e1 + e2*e2 + e3*e3 + e4*e4;
  #pragma unroll
  for (int m = 1; m < 64; m <<= 1) ss += __shfl_xor(ss, m);
  float sc = 1.0f / fmaxf(sqrtf(ss), 1e-8f);
  size_t base = ((size_t)b * S_LEN + s) * KP;
  float xs[5] = { e0*sc, e1*sc, e2*sc, e3*sc, (lane + 256 < D_EMB) ? e4*sc : 0.f };
  #pragma unroll
  for (int i = 0; i < 5; ++i) {
    unsigned short hi = f32_to_bf16(xs[i]);
    unsigned short lo = f32_to_bf16(xs[i] - bf16_to_f32(hi));
    xh[base + lane + 64*i] = hi;
    xl[base + lane + 64*i] = lo;
  }
}

// ---------------------------------------------------------------------------
// K2: feats[i][b] = max_{j<i} dot(xn[i,b], xn[j,b]); feats[0]=0
// Split-bf16 MFMA 32x32x16 (hi*hi + hi*lo + lo*hi).
// ---------------------------------------------------------------------------
#define KC  80
#define LDP 88      // LDS row stride in ushorts (conflict-friendly, 16B aligned)

__global__ __launch_bounds__(256) void k2_feats(
    const unsigned short* __restrict__ xh, const unsigned short* __restrict__ xl,
    float* __restrict__ feats) {
  __shared__ __align__(16) unsigned short sAh[64*LDP], sAl[64*LDP], sBh[64*LDP], sBl[64*LDP];
  __shared__ float rbuf[4][32];
  int ic  = blockIdx.x;          // 0..7
  int b   = blockIdx.y;          // 0..127
  int tid = threadIdx.x;
  int wave = tid >> 6, lane = tid & 63;
  int itl = wave & 1, jtl = wave >> 1;
  int itg = ic * 2 + itl;        // global 32-row i-tile index
  size_t xbase = (size_t)b * S_LEN * KP;
  int arow0 = ic * 64;

  float rm[16];
  #pragma unroll
  for (int r = 0; r < 16; ++r) rm[r] = -INFINITY;

  for (int jc = 0; jc <= ic; ++jc) {
    int jt = jc * 2 + jtl;
    bool active = (jt <= itg);
    float16v acc;
    #pragma unroll
    for (int r = 0; r < 16; ++r) acc[r] = 0.f;

    for (int kc = 0; kc < 4; ++kc) {
      __syncthreads();
      for (int u = tid; u < 640; u += 256) {     // 64 rows x 10 16B-segs
        int r = u / 10, sg = u % 10;
        size_t ga = xbase + (size_t)(arow0 + r) * KP + kc*KC + sg*8;
        size_t gb = xbase + (size_t)(jc*64 + r) * KP + kc*KC + sg*8;
        int la = r * LDP + sg * 8;
        *(ushort8*)&sAh[la] = *(const ushort8*)&xh[ga];
        *(ushort8*)&sAl[la] = *(const ushort8*)&xl[ga];
        *(ushort8*)&sBh[la] = *(const ushort8*)&xh[gb];
        *(ushort8*)&sBl[la] = *(const ushort8*)&xl[gb];
      }
      __syncthreads();
      if (active) {
        int ar = (itl*32 + (lane & 31)) * LDP;
        int br = (jtl*32 + (lane & 31)) * LDP;
        int kq = (lane >> 5) * 8;
        #pragma unroll
        for (int ks = 0; ks < 5; ++ks) {
          short8 a_h = *(const short8*)&sAh[ar + ks*16 + kq];
          short8 a_l = *(const short8*)&sAl[ar + ks*16 + kq];
          short8 b_h = *(const short8*)&sBh[br + ks*16 + kq];
          short8 b_l = *(const short8*)&sBl[br + ks*16 + kq];
          acc = __builtin_amdgcn_mfma_f32_32x32x16_bf16(a_h, b_h, acc, 0, 0, 0);
          acc = __builtin_amdgcn_mfma_f32_32x32x16_bf16(a_h, b_l, acc, 0, 0, 0);
          acc = __builtin_amdgcn_mfma_f32_32x32x16_bf16(a_l, b_h, acc, 0, 0, 0);
        }
      }
    }
    if (active) {
      int colg = jt * 32 + (lane & 31);
      #pragma unroll
      for (int r = 0; r < 16; ++r) {
        int rowg = itg * 32 + (r & 3) + 8*(r >> 2) + 4*(lane >> 5);
        float v = acc[r];
        if (jt == itg && colg >= rowg) v = -INFINITY;  // causal: j<i
        rm[r] = fmaxf(rm[r], v);
      }
    }
  }
  #pragma unroll
  for (int r = 0; r < 16; ++r) {
    float v = rm[r];
    v = fmaxf(v, __shfl_xor(v, 1));
    v = fmaxf(v, __shfl_xor(v, 2));
    v = fmaxf(v, __shfl_xor(v, 4));
    v = fmaxf(v, __shfl_xor(v, 8));
    v = fmaxf(v, __shfl_xor(v, 16));
    rm[r] = v;
  }
  if ((lane & 31) == 0) {
    int half = lane >> 5;
    #pragma unroll
    for (int r = 0; r < 16; ++r)
      rbuf[wave][(r & 3) + 8*(r >> 2) + 4*half] = rm[r];
  }
  __syncthreads();
  if (tid < 64) {   // merge jt-parities, write feats
    int it2 = tid >> 5, rl = tid & 31;
    float v = fmaxf(rbuf[it2][rl], rbuf[it2 + 2][rl]);
    int i = ic * 64 + it2 * 32 + rl;
    feats[i * B_N + b] = (i == 0) ? 0.0f : v;
  }
}

// ---------------------------------------------------------------------------
// K3: GRU, persistent cooperative kernel. 256 WGs x 256 thr.
// group g = blockIdx&7 (16 batches; same-XCD via %8 round-robin — this keeps
// the h exchange L2-local, verified by FETCH=78MB vs 4.2GB of load traffic),
// slice s = blockIdx>>3 (16 j's). W_hh split-bf16 stationary in registers.
// Sync per step: per-WG flag store (relaxed agent, no RMW) + all-wave
// parallel 32-flag poll. LDS reduce in padded [16][17] scalar layout.
// ---------------------------------------------------------------------------
#define HW2 (B_N * H_N / 2)   // uints per plane per buffer

__global__ __launch_bounds__(256, 1) void k3_gru(
    const float* __restrict__ feats,
    const float* __restrict__ w_ih, const float* __restrict__ w_hh,
    const float* __restrict__ b_ih, const float* __restrict__ b_hh,
    const float* __restrict__ fc_w, const float* __restrict__ fc_b,
    unsigned int* __restrict__ hhw, unsigned int* __restrict__ hlw,
    unsigned int* __restrict__ bars, float* __restrict__ out) {
  __shared__ float red[4][3][16][17];
  __shared__ float sfeats[S_LEN * 16];
  __shared__ float osum[256];
  int tid = threadIdx.x;
  int wave = tid >> 6, lane = tid & 63;
  int g = blockIdx.x & 7, s = blockIdx.x >> 3;

  // --- stationary W_hh fragments in registers (B-operand: n=lane&15, k=quad*8+j)
  short8 wfh[3][4], wfl[3][4];
  {
    int nloc = lane & 15;
    int kq = (lane >> 4) * 8;
    #pragma unroll
    for (int gt = 0; gt < 3; ++gt) {
      const float* wr = w_hh + (size_t)(gt * H_N + s * 16 + nloc) * H_N;
      #pragma unroll
      for (int ks = 0; ks < 4; ++ks) {
        int k0 = wave * 128 + ks * 32 + kq;
        short8 h8, l8;
        #pragma unroll
        for (int j = 0; j < 8; ++j) {
          float wv = wr[k0 + j];
          unsigned short hi = f32_to_bf16(wv);
          unsigned short lo = f32_to_bf16(wv - bf16_to_f32(hi));
          h8[j] = (short)hi; l8[j] = (short)lo;
        }
        wfh[gt][ks] = h8; wfl[gt][ks] = l8;
      }
    }
  }
  // --- stage this group's feats column into LDS: sfeats[t*16 + b_local]
  for (int u = tid; u < S_LEN * 16; u += 256)
    sfeats[u] = feats[(u >> 4) * B_N + g * 16 + (u & 15)];

  // --- per-thread gate constants: thread = (bb, jj)
  int bb = tid >> 4, jj = tid & 15;
  int jr = s * 16 + jj;
  float wihr = w_ih[jr], wihz = w_ih[H_N + jr], wihn = w_ih[2*H_N + jr];
  float bir = b_ih[jr],  biz = b_ih[H_N + jr],  bin_ = b_ih[2*H_N + jr];
  float bhr = b_hh[jr],  bhz = b_hh[H_N + jr],  bhn = b_hh[2*H_N + jr];
  float fcw = fc_w[jr];
  int gb = g * 16 + bb;
  float h_old = 0.f;
  const unsigned int* fp = bars + g * 32 + (lane & 31);  // this group's 32 flags
  unsigned int* myflag = bars + g * 32 + s;
  int arow = g * 16 + (lane & 15);              // A-operand m = batch
  int kqa = (lane >> 4) * 8;
  size_t widx = ((size_t)gb * H_N + jr) >> 1;   // h word index for this thread
  __syncthreads();   // sfeats ready

  for (int t = 0; t < S_LEN; ++t) {
    float sr = 0.f, sz = 0.f, sn = 0.f;
    if (t > 0) {
      // ---- wait: all 32 WGs stored h_{t-1} (flag >= t). every wave polls.
      {
        const unsigned tgt = (unsigned)t;
        for (;;) {
          unsigned f = __hip_atomic_load(fp, __ATOMIC_RELAXED, __HIP_MEMORY_SCOPE_AGENT);
          if (__ballot(f < tgt) == 0ull) break;
          __builtin_amdgcn_s_sleep(1);
        }
        asm volatile("" ::: "memory");
      }
      int ri = (t - 1) & 1;
      const unsigned int* bh = hhw + (size_t)ri * HW2 + (((size_t)arow * H_N) >> 1);
      const unsigned int* bl = hlw + (size_t)ri * HW2 + (((size_t)arow * H_N) >> 1);
      short8 ah[4], al[4];
      #pragma unroll
      for (int ks = 0; ks < 4; ++ks) {
        int kw = (wave * 128 + ks * 32 + kqa) >> 1;   // uint index, 8B aligned
        union { unsigned long long q[2]; short8 v; } uh, ul;
        const unsigned long long* p8h = (const unsigned long long*)(bh + kw);
        const unsigned long long* p8l = (const unsigned long long*)(bl + kw);
        uh.q[0] = __hip_atomic_load(p8h,     __ATOMIC_RELAXED, __HIP_MEMORY_SCOPE_AGENT);
        uh.q[1] = __hip_atomic_load(p8h + 1, __ATOMIC_RELAXED, __HIP_MEMORY_SCOPE_AGENT);
        ul.q[0] = __hip_atomic_load(p8l,     __ATOMIC_RELAXED, __HIP_MEMORY_SCOPE_AGENT);
        ul.q[1] = __hip_atomic_load(p8l + 1, __ATOMIC_RELAXED, __HIP_MEMORY_SCOPE_AGENT);
        ah[ks] = uh.v; al[ks] = ul.v;
      }
      float4v a0, a1, a2;
      #pragma unroll
      for (int r = 0; r < 4; ++r) { a0[r] = 0.f; a1[r] = 0.f; a2[r] = 0.f; }
      #pragma unroll
      for (int ks = 0; ks < 4; ++ks) {
        a0 = __builtin_amdgcn_mfma_f32_16x16x32_bf16(ah[ks], wfh[0][ks], a0, 0,0,0);
        a1 = __builtin_amdgcn_mfma_f32_16x16x32_bf16(ah[ks], wfh[1][ks], a1, 0,0,0);
        a2 = __builtin_amdgcn_mfma_f32_16x16x32_bf16(ah[ks], wfh[2][ks], a2, 0,0,0);
        a0 = __builtin_amdgcn_mfma_f32_16x16x32_bf16(ah[ks], wfl[0][ks], a0, 0,0,0);
        a1 = __builtin_amdgcn_mfma_f32_16x16x32_bf16(ah[ks], wfl[1][ks], a1, 0,0,0);
        a2 = __builtin_amdgcn_mfma_f32_16x16x32_bf16(ah[ks], wfl[2][ks], a2, 0,0,0);
        a0 = __builtin_amdgcn_mfma_f32_16x16x32_bf16(al[ks], wfh[0][ks], a0, 0,0,0);
        a1 = __builtin_amdgcn_mfma_f32_16x16x32_bf16(al[ks], wfh[1][ks], a1, 0,0,0);
        a2 = __builtin_amdgcn_mfma_f32_16x16x32_bf16(al[ks], wfh[2][ks], a2, 0,0,0);
      }
      // C/D: row(batch)=(lane>>4)*4+reg, col(j)=lane&15. Scalar writes, padded.
      int colw = lane & 15, roww = (lane >> 4) * 4;
      #pragma unroll
      for (int r = 0; r < 4; ++r) {
        red[wave][0][roww + r][colw] = a0[r];
        red[wave][1][roww + r][colw] = a1[r];
        red[wave][2][roww + r][colw] = a2[r];
      }
      __syncthreads();
      sr = red[0][0][bb][jj] + red[1][0][bb][jj] + red[2][0][bb][jj] + red[3][0][bb][jj];
      sz = red[0][1][bb][jj] + red[1][1][bb][jj] + red[2][1][bb][jj] + red[3][1][bb][jj];
      sn = red[0][2][bb][jj] + red[1][2][bb][jj] + red[2][2][bb][jj] + red[3][2][bb][jj];
    }
    float x = sfeats[t * 16 + bb];
    // gates: exact identities on fast exp; clamp to dodge inf/inf
    float ar_ = fminf(fmaxf(x * wihr + bir + sr + bhr, -30.f), 30.f);
    float az_ = fminf(fmaxf(x * wihz + biz + sz + bhz, -30.f), 30.f);
    float r_ = __builtin_amdgcn_rcpf(1.f + __expf(-ar_));
    float z_ = __builtin_amdgcn_rcpf(1.f + __expf(-az_));
    float an_ = fminf(fmaxf(x * wihn + bin_ + r_ * (sn + bhn), -30.f), 30.f);
    float en = __expf(-2.f * an_);
    float n_ = (1.f - en) * __builtin_amdgcn_rcpf(1.f + en);
    float h_new = (1.f - z_) * n_ + z_ * h_old;
    h_old = h_new;
    if (t < S_LEN - 1) {
      int wi = t & 1;
      unsigned short hi16 = f32_to_bf16(h_new);
      unsigned short lo16 = f32_to_bf16(h_new - bf16_to_f32(hi16));
      unsigned packed = (unsigned)hi16 | ((unsigned)lo16 << 16);
      unsigned other = (unsigned)__shfl_xor((int)packed, 1);
      if ((jj & 1) == 0) {  // hi-plane word: hi(j0) | hi(j1)<<16
        unsigned w = (packed & 0xffffu) | (other << 16);
        __hip_atomic_store(&hhw[(size_t)wi * HW2 + widx], w,
                           __ATOMIC_RELAXED, __HIP_MEMORY_SCOPE_AGENT);
      } else {              // lo-plane word: lo(j0) | lo(j1)<<16
        unsigned w = (other >> 16) | (packed & 0xffff0000u);
        __hip_atomic_store(&hlw[(size_t)wi * HW2 + widx], w,
                           __ATOMIC_RELAXED, __HIP_MEMORY_SCOPE_AGENT);
      }
      // __syncthreads() drains vmcnt (h stores at L2) before flag release
      __syncthreads();
      if (tid == 0)
        __hip_atomic_store(myflag, (unsigned)(t + 1),
                           __ATOMIC_RELAXED, __HIP_MEMORY_SCOPE_AGENT);
    }
  }
  // --- epilogue: out[b] = h_last . fc_w + fc_b
  osum[tid] = h_old * fcw;
  __syncthreads();
  if (jj == 0) {
    float acc = 0.f;
    #pragma unroll
    for (int q = 0; q < 16; ++q) acc += osum[bb * 16 + q];
    if (s == 0) acc += fc_b[0];
    atomicAdd(&out[gb], acc);
  }
}

// ---------------------------------------------------------------------------
extern "C" void kernel_launch(void* const* d_in, const int* in_sizes, int n_in,
                              void* d_out, int out_size, void* d_ws, size_t ws_size,
                              hipStream_t stream) {
  (void)in_sizes; (void)n_in; (void)out_size; (void)ws_size;
  const int*   ends = (const int*)d_in[1];
  const float* emb  = (const float*)d_in[3];
  const float* w_ih = (const float*)d_in[4];
  const float* w_hh = (const float*)d_in[5];
  const float* b_ih = (const float*)d_in[6];
  const float* b_hh = (const float*)d_in[7];
  const float* fc_w = (const float*)d_in[8];
  const float* fc_b = (const float*)d_in[9];
  float* out = (float*)d_out;

  size_t xn_elems = (size_t)B_N * S_LEN * KP;
  unsigned short* xh = (unsigned short*)d_ws;
  unsigned short* xl = xh + xn_elems;
  float* feats = (float*)(xl + xn_elems);
  unsigned int* hhw = (unsigned int*)(feats + S_LEN * B_N);
  unsigned int* hlw = hhw + 2 * (size_t)HW2;
  unsigned int* bars = hlw + 2 * (size_t)HW2;

  hipMemsetAsync(out, 0, sizeof(float) * B_N, stream);
  hipMemsetAsync(bars, 0, 4096, stream);

  k1_embed_norm<<<dim3(S_LEN * B_N / 4), dim3(256), 0, stream>>>(ends, emb, xh, xl);
  k2_feats<<<dim3(8, B_N), dim3(256), 0, stream>>>(xh, xl, feats);

  void* args[] = { (void*)&feats, (void*)&w_ih, (void*)&w_hh, (void*)&b_ih,
                   (void*)&b_hh, (void*)&fc_w, (void*)&fc_b,
                   (void*)&hhw, (void*)&hlw, (void*)&bars, (void*)&out };
  hipLaunchCooperativeKernel((void*)k3_gru, dim3(256), dim3(256), args, 0, stream);
}